// Round 8
// baseline (577.284 us; speedup 1.0000x reference)
//
#include <hip/hip_runtime.h>

#define HIDDEN 4096
#define INTER  11008
#define MTOK   128          // B*S
#define NMERG  (2*INTER)    // 22016
#define KS1    1            // stage-1: grid is 688 n-blocks, no K-split
#define KS2    4            // stage-2 K-split (fp32 partials, 8.4 MB)
#define SKB    256          // super-tile k-depth = 256 k = 256 B/row (int8)
#define RSTB   272          // LDS row stride (bytes): 256 data + 16 pad
#define TILEB  (32*RSTB)    // 8704 B per buffer

typedef short          short8  __attribute__((ext_vector_type(8)));
typedef unsigned short ushort8 __attribute__((ext_vector_type(8)));
typedef float          f32x16  __attribute__((ext_vector_type(16)));
#define AS1 __attribute__((address_space(1)))
#define AS3 __attribute__((address_space(3)))

static __device__ __forceinline__ unsigned short f2bf_rne(float f) {
    unsigned u = __builtin_bit_cast(unsigned, f);
    u += 0x7FFFu + ((u >> 16) & 1u);
    return (unsigned short)(u >> 16);
}
static __device__ __forceinline__ float bf2f(unsigned short b) {
    unsigned u = (unsigned)b << 16;
    return __builtin_bit_cast(float, u);
}
// pack two fp32 -> bf16x2 by truncation (exact for integer-valued weights)
static __device__ __forceinline__ int pk2(float lo, float hi) {
    return (int)__builtin_amdgcn_perm(__builtin_bit_cast(unsigned, hi),
                                      __builtin_bit_cast(unsigned, lo),
                                      0x07060302u);
}

// ---- weights fp32 -> int8, pure sequential both sides (m13 streaming pattern) ----
// Values are integers in [-128,127] -> int8 EXACT; gemm re-expands to bf16
// (also exact), so numerics are bit-identical to the fp32 path.
__global__ void wconv_k(const float* __restrict__ src, unsigned* __restrict__ dst) {
    size_t i = (size_t)blockIdx.x * 256 + threadIdx.x;   // one thread = 8 floats -> 8 B
    const float* s = src + i * 8;
    float4 v0 = *(const float4*)(s);
    float4 v1 = *(const float4*)(s + 4);
    unsigned lo = ((unsigned)(int)v0.x & 0xff) | (((unsigned)(int)v0.y & 0xff) << 8) |
                  (((unsigned)(int)v0.z & 0xff) << 16) | (((unsigned)(int)v0.w) << 24);
    unsigned hi = ((unsigned)(int)v1.x & 0xff) | (((unsigned)(int)v1.y & 0xff) << 8) |
                  (((unsigned)(int)v1.z & 0xff) << 16) | (((unsigned)(int)v1.w) << 24);
    uint2 o; o.x = lo; o.y = hi;
    *(uint2*)(dst + i * 2) = o;
}

// ---- x fp32 -> bf16 in MFMA A-fragment order ----
// A2[((kstep*4+ms)*64+lane)*8 + j] = bf16(x[m][k]), m=ms*32+(lane&31), k=kstep*16+(lane>>5)*8+j
__global__ void cvt_x_k(const float* __restrict__ x, unsigned short* __restrict__ A2) {
    int f = blockIdx.x * 256 + threadIdx.x;
    int lane = f & 63, w = f >> 6;
    int kstep = w >> 2, ms = w & 3;
    int m = ms * 32 + (lane & 31);
    int k = kstep * 16 + (lane >> 5) * 8;
    const float* src = x + (size_t)m * HIDDEN + k;
    float4 v0 = *(const float4*)(src);
    float4 v1 = *(const float4*)(src + 4);
    ushort8 o;
    o[0] = f2bf_rne(v0.x); o[1] = f2bf_rne(v0.y); o[2] = f2bf_rne(v0.z); o[3] = f2bf_rne(v0.w);
    o[4] = f2bf_rne(v1.x); o[5] = f2bf_rne(v1.y); o[6] = f2bf_rne(v1.z); o[7] = f2bf_rne(v1.w);
    *(ushort8*)(A2 + (size_t)f * 8) = o;
}

// ---- dequant GEMM partial on INT8 weights (r4 structure, 4x fewer bytes) ----
// BN=32 rows/block, SK=256 k (256 B/row int8). 4 waves split M (wave ws owns
// m ws*32..+31) and share the B-tile: block-coop staging (8 rows/wave, one
// size-4 global_load_lds per row), raw s_barrier + counted vmcnt(24) pipeline
// (never drains in-loop; r4-verified discipline). A-fragments register-
// double-buffered so the compute phase has zero VMEM (r2 lesson). int8 is
// expanded to bf16 in-register before MFMA (exact; VALU has 90% headroom).
template<bool OBF16>
__global__ __launch_bounds__(256) void gemm_k(
    const unsigned short* __restrict__ A2,
    const char* __restrict__ Bq,        // packed [N][K] int8 row-major
    void* __restrict__ part, int K /*k elems = bytes per row*/, int N,
    int totTiles, int ksplit)
{
    __shared__ __align__(16) char lds[2 * TILEB];   // 17408 B
    const int lane = threadIdx.x & 63;
    const int ws   = threadIdx.x >> 6;
    const int n0   = blockIdx.x * 32;
    const int ks   = blockIdx.y;
    const int tbeg = (ks * totTiles) / ksplit;
    const int tend = ((ks + 1) * totTiles) / ksplit;
    const int nt   = tend - tbeg;

    // 8 rows this wave stages; one instr = 64 lanes x 4B = 256B of ONE row
    const char* rowp[8];
#pragma unroll
    for (int r = 0; r < 8; ++r)
        rowp[r] = Bq + (size_t)(n0 + ws * 8 + r) * K + lane * 4;

    f32x16 acc;
#pragma unroll
    for (int r = 0; r < 16; ++r) acc[r] = 0.f;

    auto stage = [&](int t, int buf) {
        const size_t koff = (size_t)t * SKB;
#pragma unroll
        for (int r = 0; r < 8; ++r) {
            __builtin_amdgcn_global_load_lds(
                (const AS1 unsigned*)(rowp[r] + koff),
                (AS3 unsigned*)(lds + buf * TILEB + (ws * 8 + r) * RSTB), 4, 0, 0);
        }
    };
    auto loadA = [&](int t, short8 (&Ar)[16]) {
#pragma unroll
        for (int s = 0; s < 16; ++s) {
            int kg = t * 16 + s;                   // global 16-k step
            Ar[s] = *(const short8*)(A2 + ((size_t)(kg * 4 + ws) * 64 + lane) * 8);
        }
    };

    short8 A0v[16], A1v[16];

    auto iter = [&](int i, short8 (&Ar)[16]) {
        // own stage(i)+A(i) retired; stage(i+1)+A(i+1) (24 newest) in flight
        if (i + 1 < nt) { asm volatile("s_waitcnt vmcnt(24)" ::: "memory"); }
        else            { asm volatile("s_waitcnt vmcnt(0)"  ::: "memory"); }
        __builtin_amdgcn_sched_barrier(0);
        __builtin_amdgcn_s_barrier();              // all waves' tile-i writes landed

        const char* lb = lds + (size_t)(i & 1) * TILEB
                       + (lane & 31) * RSTB + (lane >> 5) * 8;
#pragma unroll
        for (int s = 0; s < 16; ++s) {
            uint2 d = *(const uint2*)(lb + s * 16);
            float f0 = (float)(signed char)(d.x);
            float f1 = (float)(signed char)(d.x >> 8);
            float f2 = (float)(signed char)(d.x >> 16);
            float f3 = (float)(signed char)(d.x >> 24);
            float f4 = (float)(signed char)(d.y);
            float f5 = (float)(signed char)(d.y >> 8);
            float f6 = (float)(signed char)(d.y >> 16);
            float f7 = (float)(signed char)(d.y >> 24);
            int4 bi;
            bi.x = pk2(f0, f1); bi.y = pk2(f2, f3);
            bi.z = pk2(f4, f5); bi.w = pk2(f6, f7);
            short8 bf = __builtin_bit_cast(short8, bi);
            acc = __builtin_amdgcn_mfma_f32_32x32x16_bf16(Ar[s], bf, acc, 0, 0, 0);
        }

        asm volatile("s_waitcnt lgkmcnt(0)" ::: "memory");   // WAR: ds_reads done
        __builtin_amdgcn_sched_barrier(0);
        __builtin_amdgcn_s_barrier();              // all waves done reading buf i&1
        if (i + 2 < nt) { stage(tbeg + i + 2, i & 1); loadA(tbeg + i + 2, Ar); }
    };

    // prologue: fill both buffers
    stage(tbeg, 0); loadA(tbeg, A0v);
    if (nt > 1) { stage(tbeg + 1, 1); loadA(tbeg + 1, A1v); }

    for (int i = 0; i < nt; i += 2) {
        iter(i, A0v);
        if (i + 1 < nt) iter(i + 1, A1v);
    }

    // C/D layout: col=lane&31 -> n; row=(r&3)+8*(r>>2)+4*(lane>>5) -> m (wave owns ms=ws)
    const int n = n0 + (lane & 31);
#pragma unroll
    for (int r = 0; r < 16; ++r) {
        int m = ws * 32 + (r & 3) + 8 * (r >> 2) + 4 * (lane >> 5);
        size_t idx = ((size_t)ks * MTOK + m) * (size_t)N + n;
        if (OBF16) ((unsigned short*)part)[idx] = f2bf_rne(acc[r]);
        else       ((float*)part)[idx] = acc[r];
    }
}

// ---- combine KS1 bf16 partials, scale, SwiGLU -> h in fragment order ----
__global__ void swiglu_k(const unsigned short* __restrict__ p1,  // [KS1][MTOK][NMERG] bf16
                         const float* __restrict__ s1, const float* __restrict__ s3,
                         unsigned short* __restrict__ h2)        // fragment-ordered, K=INTER
{
    int f = blockIdx.x * 256 + threadIdx.x;
    int lane = f & 63, w = f >> 6;
    int kstep = w >> 2, ms = w & 3;
    int m = ms * 32 + (lane & 31);
    int j = kstep * 16 + (lane >> 5) * 8;
    float up[8], gt[8];
#pragma unroll
    for (int e = 0; e < 8; ++e) { up[e] = 0.f; gt[e] = 0.f; }
#pragma unroll
    for (int ks = 0; ks < KS1; ++ks) {
        const unsigned short* pu = p1 + ((size_t)ks * MTOK + m) * NMERG + j;
        ushort8 u = *(const ushort8*)(pu);
        ushort8 g = *(const ushort8*)(pu + INTER);
#pragma unroll
        for (int e = 0; e < 8; ++e) { up[e] += bf2f(u[e]); gt[e] += bf2f(g[e]); }
    }
    float4 c1a = *(const float4*)(s1 + j), c1b = *(const float4*)(s1 + j + 4);
    float4 c3a = *(const float4*)(s3 + j), c3b = *(const float4*)(s3 + j + 4);
    float c1[8] = {c1a.x, c1a.y, c1a.z, c1a.w, c1b.x, c1b.y, c1b.z, c1b.w};
    float c3[8] = {c3a.x, c3a.y, c3a.z, c3a.w, c3b.x, c3b.y, c3b.z, c3b.w};
    ushort8 o;
#pragma unroll
    for (int e = 0; e < 8; ++e) {
        float u = up[e] * c1[e], g = gt[e] * c3[e];
        o[e] = f2bf_rne(g * u / (1.f + __expf(-u)));
    }
    *(ushort8*)(h2 + (size_t)f * 8) = o;
}

// ---- reduce KS2 fp32 partials, scale by w2_s ----
__global__ void reduce_k(const float* __restrict__ p, const float* __restrict__ s2,
                         float* __restrict__ out)
{
    int i = (blockIdx.x * 256 + threadIdx.x) * 4;
    float4 acc = *(const float4*)(p + i);
#pragma unroll
    for (int s = 1; s < KS2; ++s) {
        float4 v = *(const float4*)(p + (size_t)s * MTOK * HIDDEN + i);
        acc.x += v.x; acc.y += v.y; acc.z += v.z; acc.w += v.w;
    }
    int ncol = i & (HIDDEN - 1);
    float4 sc = *(const float4*)(s2 + ncol);
    acc.x *= sc.x; acc.y *= sc.y; acc.z *= sc.z; acc.w *= sc.w;
    *(float4*)(out + i) = acc;
}

extern "C" void kernel_launch(void* const* d_in, const int* in_sizes, int n_in,
                              void* d_out, int out_size, void* d_ws, size_t ws_size,
                              hipStream_t stream) {
    const float* x   = (const float*)d_in[0];
    const float* w1q = (const float*)d_in[1];
    const float* w1s = (const float*)d_in[2];
    const float* w3q = (const float*)d_in[3];
    const float* w3s = (const float*)d_in[4];
    const float* w2q = (const float*)d_in[5];
    const float* w2s = (const float*)d_in[6];
    float* out = (float*)d_out;

    const size_t WB = (size_t)INTER * HIDDEN;      // 45,088,768 elems per matrix

    char* ws = (char*)d_ws;
    unsigned short* xb2 = (unsigned short*)ws;                 // 1 MB    fragment-ordered x
    unsigned short* h2  = (unsigned short*)(ws + (1u << 20));  // 2.75 MB fragment-ordered h
    void* part          = (void*)(ws + (4u << 20));            // 5.5 MB bf16 / 8.4 MB fp32
    char* wi8           = (char*)(ws + (16u << 20));           // int8 weights (max 90.2 MB)

    const int NCONV = (int)(WB / 8 / 256);                     // 22016 blocks

    // 1) w1,w3 -> int8 (packed adjacently => one merged [22016][4096] matrix)
    wconv_k<<<NCONV, 256, 0, stream>>>(w1q, (unsigned*)wi8);
    wconv_k<<<NCONV, 256, 0, stream>>>(w3q, (unsigned*)(wi8 + WB));
    // 2) x -> bf16 fragments
    cvt_x_k<<<MTOK * HIDDEN / 8 / 256, 256, 0, stream>>>(x, xb2);
    // 3) up/gate: N=22016, K=4096 (16 super-tiles), no K-split -> bf16 part
    gemm_k<true><<<dim3(NMERG / 32, KS1), 256, 0, stream>>>(
        xb2, wi8, part, HIDDEN, NMERG, HIDDEN / SKB, KS1);
    // 4) SwiGLU -> h fragments
    swiglu_k<<<MTOK * INTER / 8 / 256, 256, 0, stream>>>(
        (const unsigned short*)part, w1s, w3s, h2);
    // 5) w2 -> int8 (reuses w1's region; w1/w3 int8 are dead now)
    wconv_k<<<NCONV, 256, 0, stream>>>(w2q, (unsigned*)wi8);
    // 6) out: N=4096, K=11008 (43 super-tiles), K-split 4 -> fp32 partials
    gemm_k<false><<<dim3(HIDDEN / 32, KS2), 256, 0, stream>>>(
        h2, wi8, part, INTER, HIDDEN, INTER / SKB, KS2);
    // 7) reduce + scale
    reduce_k<<<MTOK * HIDDEN / 4 / 256, 256, 0, stream>>>(
        (const float*)part, w2s, out);
}